// Round 13
// baseline (402.711 us; speedup 1.0000x reference)
//
#include <hip/hip_runtime.h>

#define N_NODES 50000
#define N_EDGES 800000
#define NB512 98              // cdiv(N, 512)
#define DBINS 64              // degree bins for balance sort

static inline int cdiv(int a, int b) { return (a + b - 1) / b; }

typedef __attribute__((ext_vector_type(8))) short s8vec;   // 8 x bf16 (4 VGPRs)
typedef __attribute__((ext_vector_type(4))) float f32x4;   // MFMA accumulator

// fp32 -> bf16 round-to-nearest-even
__device__ inline ushort f2b(float f) {
    uint u = __float_as_uint(f);
    uint r = (u + 0x7fffu + ((u >> 16) & 1u)) >> 16;
    return (ushort)r;
}
__device__ inline float b2f_lo(uint v) { return __uint_as_float(v << 16); }
__device__ inline float b2f_hi(uint v) { return __uint_as_float(v & 0xffff0000u); }

__device__ inline void add8(float* acc, uint4 v) {
    acc[0] += b2f_lo(v.x); acc[1] += b2f_hi(v.x);
    acc[2] += b2f_lo(v.y); acc[3] += b2f_hi(v.y);
    acc[4] += b2f_lo(v.z); acc[5] += b2f_hi(v.z);
    acc[6] += b2f_lo(v.w); acc[7] += b2f_hi(v.w);
}

// ---------------- prep: zero cnt+dhist ∥ weight transpose+convert ----------------

__global__ __launch_bounds__(256) void k_prep(int* cnt, int* dhist,
                                              const float* __restrict__ W0, const float* __restrict__ W1,
                                              const float* __restrict__ W2, const float* __restrict__ Wo,
                                              ushort* Wt0, ushort* Wt1, ushort* Wt2, ushort* Wto) {
    int b = blockIdx.x;
    if (b < 196) {
        int i = b * 256 + threadIdx.x;
        if (i < N_NODES) cnt[i] = 0;
        if (b == 0 && threadIdx.x < DBINS) dhist[threadIdx.x] = 0;
        return;
    }
    int i = (b - 196) * 256 + threadIdx.x;
    if (i < 16384) {
        int nn = i >> 7, k = i & 127;
        Wt0[i] = f2b(W0[k * 128 + nn]);
    } else if (i < 32768) {
        int j = i - 16384; int nn = j >> 7, k = j & 127;
        Wt1[j] = f2b(W1[k * 128 + nn]);
    } else if (i < 49152) {
        int j = i - 32768; int nn = j >> 7, k = j & 127;
        Wt2[j] = f2b(W2[k * 128 + nn]);
    } else if (i < 57344) {
        int j = i - 49152; int nn = j >> 7, k = j & 127;
        Wto[j] = f2b(Wo[k * 64 + nn]);
    }
}

// count + per-edge rank (atomic return value = rank within dst)
__global__ __launch_bounds__(256) void k_count(const int* __restrict__ dst, int* cnt,
                                               int* __restrict__ rank, int e) {
    int i = blockIdx.x * 256 + threadIdx.x;
    if (i < e) rank[i] = atomicAdd(&cnt[dst[i]], 1);
}

// ---------------- single-kernel scan + degree histogram ----------------
// writes rowptr, dinv; accumulates dhist (LDS-staged)

__global__ __launch_bounds__(512) void k_scan_all(const int* __restrict__ cnt,
                                                  int* rowptr, float* dinv, int* dhist,
                                                  int n, int e, int nb) {
    __shared__ int sh[512];
    __shared__ int lh[DBINS];
    int t = threadIdx.x, b = blockIdx.x;
    int start = b * 512;
    if (t < DBINS) lh[t] = 0;

    int partial = 0;
    for (int i = t; i < start; i += 512) partial += cnt[i];
    sh[t] = partial;
    __syncthreads();
    for (int off = 256; off > 0; off >>= 1) {
        if (t < off) sh[t] += sh[t + off];
        __syncthreads();
    }
    int base = sh[0];
    __syncthreads();

    int i = start + t;
    int v = (i < n) ? cnt[i] : 0;
    sh[t] = v;
    __syncthreads();
    for (int off = 1; off < 512; off <<= 1) {
        int add = (t >= off) ? sh[t - off] : 0;
        __syncthreads();
        sh[t] += add;
        __syncthreads();
    }
    if (i < n) {
        rowptr[i] = base + sh[t] - v;   // exclusive
        dinv[i] = rsqrtf((float)v + 1.0f);
        atomicAdd(&lh[v < DBINS ? v : DBINS - 1], 1);
    }
    __syncthreads();
    if (t < DBINS && lh[t]) atomicAdd(&dhist[t], lh[t]);
    if (b == nb - 1 && t == 0) rowptr[n] = e;
}

// exclusive scan of 64-bin degree histogram -> dcur (cursors)
__global__ __launch_bounds__(64) void k_dscan(const int* __restrict__ dhist, int* dcur) {
    __shared__ int sh[DBINS];
    int t = threadIdx.x;
    int v = dhist[t];
    sh[t] = v;
    __syncthreads();
    for (int off = 1; off < DBINS; off <<= 1) {
        int add = (t >= off) ? sh[t - off] : 0;
        __syncthreads();
        sh[t] += add;
        __syncthreads();
    }
    dcur[t] = sh[t] - v;   // exclusive
}

// ---------------- MFMA GEMM body (2 row-tiles / wave, 128 rows / block) — layer-0 only ----------------

template <int NCOL, bool IN_F32, bool OUT_F32, bool SCALE>
__device__ inline void mm_body(const void* __restrict__ Av, const ushort* __restrict__ Wt,
                               const float* __restrict__ bias, const float* __restrict__ dinv,
                               void* __restrict__ Cv, int n, int bid) {
    constexpr int NT = NCOL / 16;
    int wave = threadIdx.x >> 6;
    int lane = threadIdx.x & 63;
    int quad = lane >> 4;
    int lm = lane & 15;
    int row0 = bid * 128 + wave * 32;

    int rA0 = row0 + lm;      if (rA0 > n - 1) rA0 = n - 1;
    int rA1 = row0 + 16 + lm; if (rA1 > n - 1) rA1 = n - 1;

    f32x4 acc[2][NT];
#pragma unroll
    for (int r = 0; r < 2; r++)
#pragma unroll
        for (int t = 0; t < NT; t++) acc[r][t] = (f32x4){0.f, 0.f, 0.f, 0.f};

    for (int kc = 0; kc < 128; kc += 32) {
        s8vec af[2];
        if (IN_F32) {
            const float* A = (const float*)Av;
#pragma unroll
            for (int r = 0; r < 2; r++) {
                const float* p = A + (size_t)(r ? rA1 : rA0) * 128 + quad * 8 + kc;
                float4 a = *(const float4*)p, b = *(const float4*)(p + 4);
                s8vec v;
                v[0] = (short)f2b(a.x); v[1] = (short)f2b(a.y);
                v[2] = (short)f2b(a.z); v[3] = (short)f2b(a.w);
                v[4] = (short)f2b(b.x); v[5] = (short)f2b(b.y);
                v[6] = (short)f2b(b.z); v[7] = (short)f2b(b.w);
                af[r] = v;
            }
        } else {
            const ushort* A = (const ushort*)Av;
            af[0] = *(const s8vec*)(A + (size_t)rA0 * 128 + quad * 8 + kc);
            af[1] = *(const s8vec*)(A + (size_t)rA1 * 128 + quad * 8 + kc);
        }
#pragma unroll
        for (int t = 0; t < NT; t++) {
            s8vec bf = *(const s8vec*)(Wt + (size_t)(t * 16 + lm) * 128 + kc + quad * 8);
            acc[0][t] = __builtin_amdgcn_mfma_f32_16x16x32_bf16(af[0], bf, acc[0][t], 0, 0, 0);
            acc[1][t] = __builtin_amdgcn_mfma_f32_16x16x32_bf16(af[1], bf, acc[1][t], 0, 0, 0);
        }
    }

#pragma unroll
    for (int r = 0; r < 2; r++) {
#pragma unroll
        for (int i = 0; i < 4; i++) {
            int rr = row0 + r * 16 + quad * 4 + i;
            if (rr < n) {
                float dv = SCALE ? dinv[rr] : 1.0f;
#pragma unroll
                for (int t = 0; t < NT; t++) {
                    int col = t * 16 + lm;
                    if (OUT_F32)
                        ((float*)Cv)[(size_t)rr * NCOL + col] = acc[r][t][i] + bias[col];
                    else
                        ((ushort*)Cv)[(size_t)rr * 128 + col] =
                            f2b(SCALE ? acc[r][t][i] * dv : acc[r][t][i]);
                }
            }
        }
    }
}

// fused: [0,mm) = layer-0 GEMM; [mm,mm+fill) = atomic-free CSR fill; rest = degree-sort scatter
__global__ __launch_bounds__(256) void k_mm0_fill(const void* __restrict__ Av,
                                                  const ushort* __restrict__ Wt,
                                                  const float* __restrict__ dinv,
                                                  void* __restrict__ Cv, int n, int mmblocks, int fillblocks,
                                                  const int* __restrict__ src, const int* __restrict__ dst,
                                                  const int* __restrict__ rank,
                                                  const int* __restrict__ rowptr,
                                                  ushort* ed,
                                                  const int* __restrict__ cnt, int* dcur, int* perm, int e) {
    int b = blockIdx.x;
    if (b >= mmblocks + fillblocks) {
        int i = (b - mmblocks - fillblocks) * 256 + threadIdx.x;
        if (i < n) {
            int deg = cnt[i];
            int bin = deg < DBINS ? deg : DBINS - 1;
            int pos = atomicAdd(&dcur[bin], 1);
            perm[pos] = i;
        }
        return;
    }
    if (b >= mmblocks) {
        int base = (b - mmblocks) * 1024 + threadIdx.x;
#pragma unroll
        for (int k = 0; k < 4; k++) {
            int i = base + k * 256;
            if (i < e) {
                int d = dst[i];
                int pos = rowptr[d] + rank[i];
                ed[pos] = (ushort)src[i];
            }
        }
        return;
    }
    mm_body<128, true, false, true>(Av, Wt, nullptr, dinv, Cv, n, b);
}

// ---------------- fused gather + next-layer GEMM (degree-balanced via perm) ----------------
// Phase 1: 16 lanes/node gather (4-wide ILP), h = relu(dinv*(sum+self)+bias)+res;
//          h rows -> LDS (272B stride) and (if !FINAL) global hout.
// Phase 2: 16-row MFMA tile: A from LDS, 4 waves x NCOL cols; rows scattered per perm.

template <int NCOL, bool RES_F32, bool FINAL>
__global__ __launch_bounds__(256) void k_gather_mm(const uint4* __restrict__ T4,
                                                   const int* __restrict__ rowptr,
                                                   const ushort* __restrict__ ed,
                                                   const float* __restrict__ dinv,
                                                   const float* __restrict__ biasL,
                                                   const void* __restrict__ resv,
                                                   uint4* __restrict__ hout,
                                                   const ushort* __restrict__ Wt,
                                                   const float* __restrict__ bias_out,
                                                   void* __restrict__ Cv,
                                                   const int* __restrict__ perm, int n) {
    __shared__ uint4 As4[16 * 17];                 // 16 rows x 272 B (16B pad)
    __shared__ int pnode[16];
    ushort* As = (ushort*)As4;

    int tid = threadIdx.x;
    int nl = tid >> 4, ql = tid & 15;
    int qb = tid & 48;                              // quarter base within the wave
    int node = perm[blockIdx.x * 16 + nl];
    if (ql == 0) pnode[nl] = node;

    // ---- phase 1: gather ----
    float acc[8] = {0.f, 0.f, 0.f, 0.f, 0.f, 0.f, 0.f, 0.f};
    int beg = rowptr[node], end = rowptr[node + 1];

    for (int base = beg; base < end; base += 16) {
        int m = end - base; if (m > 16) m = 16;
        int idx = base + ql; if (idx > end - 1) idx = end - 1;
        uint em = ed[idx];
        int j = 0;
        for (; j + 4 <= m; j += 4) {
            int s0 = __shfl((int)em, qb + j);
            int s1 = __shfl((int)em, qb + j + 1);
            int s2 = __shfl((int)em, qb + j + 2);
            int s3 = __shfl((int)em, qb + j + 3);
            uint4 v0 = T4[(size_t)s0 * 16 + ql];
            uint4 v1 = T4[(size_t)s1 * 16 + ql];
            uint4 v2 = T4[(size_t)s2 * 16 + ql];
            uint4 v3 = T4[(size_t)s3 * 16 + ql];
            add8(acc, v0); add8(acc, v1); add8(acc, v2); add8(acc, v3);
        }
        for (; j < m; j++) {
            int s = __shfl((int)em, qb + j);
            uint4 v = T4[(size_t)s * 16 + ql];
            add8(acc, v);
        }
    }

    uint4 vs = T4[(size_t)node * 16 + ql];          // self (pre-scaled)
    add8(acc, vs);

    float di = dinv[node];
    float4 bv0 = ((const float4*)biasL)[ql * 2];
    float4 bv1 = ((const float4*)biasL)[ql * 2 + 1];
    float bb[8] = {bv0.x, bv0.y, bv0.z, bv0.w, bv1.x, bv1.y, bv1.z, bv1.w};

    float r[8];
    if (RES_F32) {
        float4 r0 = ((const float4*)resv)[(size_t)node * 32 + ql * 2];
        float4 r1 = ((const float4*)resv)[(size_t)node * 32 + ql * 2 + 1];
        r[0] = r0.x; r[1] = r0.y; r[2] = r0.z; r[3] = r0.w;
        r[4] = r1.x; r[5] = r1.y; r[6] = r1.z; r[7] = r1.w;
    } else {
        uint4 rv = ((const uint4*)resv)[(size_t)node * 16 + ql];
        r[0] = b2f_lo(rv.x); r[1] = b2f_hi(rv.x); r[2] = b2f_lo(rv.y); r[3] = b2f_hi(rv.y);
        r[4] = b2f_lo(rv.z); r[5] = b2f_hi(rv.z); r[6] = b2f_lo(rv.w); r[7] = b2f_hi(rv.w);
    }

    float o[8];
#pragma unroll
    for (int i = 0; i < 8; i++)
        o[i] = fmaxf(acc[i] * di + bb[i], 0.f) + r[i];

    uint4 ov;
    ov.x = (uint)f2b(o[0]) | ((uint)f2b(o[1]) << 16);
    ov.y = (uint)f2b(o[2]) | ((uint)f2b(o[3]) << 16);
    ov.z = (uint)f2b(o[4]) | ((uint)f2b(o[5]) << 16);
    ov.w = (uint)f2b(o[6]) | ((uint)f2b(o[7]) << 16);

    if (!FINAL) hout[(size_t)node * 16 + ql] = ov;
    *(uint4*)&As[nl * 136 + ql * 8] = ov;
    __syncthreads();

    // ---- phase 2: 16-row MFMA tile on this block's h rows ----
    constexpr int NT = NCOL / 64;                   // col tiles per wave (128->2, 64->1)
    int wave = tid >> 6;
    int lane = tid & 63;
    int quad = lane >> 4;
    int lm = lane & 15;

    f32x4 macc[NT];
#pragma unroll
    for (int t = 0; t < NT; t++) macc[t] = (f32x4){0.f, 0.f, 0.f, 0.f};

    for (int kc = 0; kc < 128; kc += 32) {
        s8vec af = *(const s8vec*)&As[lm * 136 + kc + quad * 8];
#pragma unroll
        for (int t = 0; t < NT; t++) {
            int col = wave * (16 * NT) + t * 16 + lm;
            s8vec bf = *(const s8vec*)(Wt + (size_t)col * 128 + kc + quad * 8);
            macc[t] = __builtin_amdgcn_mfma_f32_16x16x32_bf16(af, bf, macc[t], 0, 0, 0);
        }
    }

#pragma unroll
    for (int t = 0; t < NT; t++) {
        int col = wave * (16 * NT) + t * 16 + lm;
#pragma unroll
        for (int i = 0; i < 4; i++) {
            int rr = pnode[quad * 4 + i];
            if (FINAL)
                ((float*)Cv)[(size_t)rr * 64 + col] = macc[t][i] + bias_out[col];
            else
                ((ushort*)Cv)[(size_t)rr * 128 + col] = f2b(macc[t][i] * dinv[rr]);
        }
    }
}

// ---------------- launch ----------------

extern "C" void kernel_launch(void* const* d_in, const int* in_sizes, int n_in,
                              void* d_out, int out_size, void* d_ws, size_t ws_size,
                              hipStream_t stream) {
    const float* x  = (const float*)d_in[0];
    const int* eidx = (const int*)d_in[1];
    const float* W0 = (const float*)d_in[2];
    const float* b0 = (const float*)d_in[3];
    const float* W1 = (const float*)d_in[4];
    const float* b1 = (const float*)d_in[5];
    const float* W2 = (const float*)d_in[6];
    const float* b2 = (const float*)d_in[7];
    const float* Wo = (const float*)d_in[8];
    const float* bo = (const float*)d_in[9];
    float* out = (float*)d_out;

    const int N = N_NODES, E = N_EDGES;
    const int* srcI = eidx;
    const int* dstI = eidx + E;

    char* ws = (char*)d_ws;
    auto alloc = [&](size_t bytes) { char* p = ws; ws += (bytes + 255) / 256 * 256; return p; };
    int*    cnt    = (int*)alloc((size_t)N * 4);
    int*    rowptr = (int*)alloc((size_t)(N + 1) * 4);
    int*    rank   = (int*)alloc((size_t)E * 4);
    int*    dhist  = (int*)alloc(DBINS * 4);
    int*    dcur   = (int*)alloc(DBINS * 4);
    int*    perm   = (int*)alloc((size_t)N * 4);
    float*  dinv   = (float*)alloc((size_t)N * 4);
    ushort* ed     = (ushort*)alloc((size_t)E * 2);
    ushort* tA     = (ushort*)alloc((size_t)N * 128 * 2);
    ushort* tB     = (ushort*)alloc((size_t)N * 128 * 2);
    ushort* hAb    = (ushort*)alloc((size_t)N * 128 * 2);
    ushort* hBb    = (ushort*)alloc((size_t)N * 128 * 2);
    ushort* Wt0    = (ushort*)alloc(128 * 128 * 2);
    ushort* Wt1    = (ushort*)alloc(128 * 128 * 2);
    ushort* Wt2    = (ushort*)alloc(128 * 128 * 2);
    ushort* Wto    = (ushort*)alloc(64 * 128 * 2);

    dim3 b256(256), b512(512);

    const int mmGrid   = cdiv(N, 128);      // 391
    const int fillGrid = cdiv(E, 1024);     // 782
    const int permGrid = cdiv(N, 256);      // 196
    const int gGrid    = N / 16;            // 3125 (exact)

    // prep (zero cnt+dhist ∥ weight transpose) -> count+rank -> scan+hist -> bin scan
    k_prep<<<196 + 224, b256, 0, stream>>>(cnt, dhist, W0, W1, W2, Wo, Wt0, Wt1, Wt2, Wto);
    k_count<<<cdiv(E, 256), b256, 0, stream>>>(dstI, cnt, rank, E);
    k_scan_all<<<NB512, b512, 0, stream>>>(cnt, rowptr, dinv, dhist, N, E, NB512);
    k_dscan<<<1, 64, 0, stream>>>(dhist, dcur);

    // layer-0 GEMM (-> tA) ∥ atomic-free CSR fill ∥ degree-sort scatter
    k_mm0_fill<<<mmGrid + fillGrid + permGrid, b256, 0, stream>>>(
        x, Wt0, dinv, tA, N, mmGrid, fillGrid, srcI, dstI, rank, rowptr, ed, cnt, dcur, perm, E);

    // gather0 (T=tA, res=x) + mm1 -> tB; h1 -> hAb
    k_gather_mm<128, true, false><<<gGrid, b256, 0, stream>>>(
        (const uint4*)tA, rowptr, ed, dinv, b0, x, (uint4*)hAb, Wt1, nullptr, tB, perm, N);

    // gather1 (T=tB, res=hAb) + mm2 -> tA; h2 -> hBb
    k_gather_mm<128, false, false><<<gGrid, b256, 0, stream>>>(
        (const uint4*)tB, rowptr, ed, dinv, b1, hAb, (uint4*)hBb, Wt2, nullptr, tA, perm, N);

    // gather2 (T=tA, res=hBb) + output projection -> out (fp32 + bias); h3 not materialized
    k_gather_mm<64, false, true><<<gGrid, b256, 0, stream>>>(
        (const uint4*)tA, rowptr, ed, dinv, b2, hBb, nullptr, Wto, bo, out, perm, N);
}

// Round 14
// 275.365 us; speedup vs baseline: 1.4625x; 1.4625x over previous
//
#include <hip/hip_runtime.h>

#define N_NODES 50000
#define N_EDGES 800000
#define NB512 98              // cdiv(N, 512)

static inline int cdiv(int a, int b) { return (a + b - 1) / b; }

typedef __attribute__((ext_vector_type(8))) short s8vec;   // 8 x bf16 (4 VGPRs)
typedef __attribute__((ext_vector_type(4))) float f32x4;   // MFMA accumulator

// fp32 -> bf16 round-to-nearest-even
__device__ inline ushort f2b(float f) {
    uint u = __float_as_uint(f);
    uint r = (u + 0x7fffu + ((u >> 16) & 1u)) >> 16;
    return (ushort)r;
}
__device__ inline float b2f_lo(uint v) { return __uint_as_float(v << 16); }
__device__ inline float b2f_hi(uint v) { return __uint_as_float(v & 0xffff0000u); }

__device__ inline void add8(float* acc, uint4 v) {
    acc[0] += b2f_lo(v.x); acc[1] += b2f_hi(v.x);
    acc[2] += b2f_lo(v.y); acc[3] += b2f_hi(v.y);
    acc[4] += b2f_lo(v.z); acc[5] += b2f_hi(v.z);
    acc[6] += b2f_lo(v.w); acc[7] += b2f_hi(v.w);
}

// ---------------- prep: zero cnt ∥ weight transpose+convert ----------------

__global__ __launch_bounds__(256) void k_prep(int* cnt,
                                              const float* __restrict__ W0, const float* __restrict__ W1,
                                              const float* __restrict__ W2, const float* __restrict__ Wo,
                                              ushort* Wt0, ushort* Wt1, ushort* Wt2, ushort* Wto) {
    int b = blockIdx.x;
    if (b < 196) {
        int i = b * 256 + threadIdx.x;
        if (i < N_NODES) cnt[i] = 0;
        return;
    }
    int i = (b - 196) * 256 + threadIdx.x;
    if (i < 16384) {
        int nn = i >> 7, k = i & 127;
        Wt0[i] = f2b(W0[k * 128 + nn]);
    } else if (i < 32768) {
        int j = i - 16384; int nn = j >> 7, k = j & 127;
        Wt1[j] = f2b(W1[k * 128 + nn]);
    } else if (i < 49152) {
        int j = i - 32768; int nn = j >> 7, k = j & 127;
        Wt2[j] = f2b(W2[k * 128 + nn]);
    } else if (i < 57344) {
        int j = i - 49152; int nn = j >> 7, k = j & 127;
        Wto[j] = f2b(Wo[k * 64 + nn]);
    }
}

// count + per-edge rank (atomic return value = rank within dst)
__global__ __launch_bounds__(256) void k_count(const int* __restrict__ dst, int* cnt,
                                               int* __restrict__ rank, int e) {
    int i = blockIdx.x * 256 + threadIdx.x;
    if (i < e) rank[i] = atomicAdd(&cnt[dst[i]], 1);
}

// ---------------- single-kernel scan: each block redundantly sums its prefix ----------------
// writes rowptr, dinv

__global__ __launch_bounds__(512) void k_scan_all(const int* __restrict__ cnt,
                                                  int* rowptr, float* dinv,
                                                  int n, int e, int nb) {
    __shared__ int sh[512];
    int t = threadIdx.x, b = blockIdx.x;
    int start = b * 512;

    int partial = 0;
    for (int i = t; i < start; i += 512) partial += cnt[i];
    sh[t] = partial;
    __syncthreads();
    for (int off = 256; off > 0; off >>= 1) {
        if (t < off) sh[t] += sh[t + off];
        __syncthreads();
    }
    int base = sh[0];
    __syncthreads();

    int i = start + t;
    int v = (i < n) ? cnt[i] : 0;
    sh[t] = v;
    __syncthreads();
    for (int off = 1; off < 512; off <<= 1) {
        int add = (t >= off) ? sh[t - off] : 0;
        __syncthreads();
        sh[t] += add;
        __syncthreads();
    }
    if (i < n) {
        rowptr[i] = base + sh[t] - v;   // exclusive
        dinv[i] = rsqrtf((float)v + 1.0f);
    }
    if (b == nb - 1 && t == 0) rowptr[n] = e;
}

// ---------------- MFMA GEMM body (2 row-tiles / wave, 128 rows / block) — layer-0 only ----------------

template <int NCOL, bool IN_F32, bool OUT_F32, bool SCALE>
__device__ inline void mm_body(const void* __restrict__ Av, const ushort* __restrict__ Wt,
                               const float* __restrict__ bias, const float* __restrict__ dinv,
                               void* __restrict__ Cv, int n, int bid) {
    constexpr int NT = NCOL / 16;
    int wave = threadIdx.x >> 6;
    int lane = threadIdx.x & 63;
    int quad = lane >> 4;
    int lm = lane & 15;
    int row0 = bid * 128 + wave * 32;

    int rA0 = row0 + lm;      if (rA0 > n - 1) rA0 = n - 1;
    int rA1 = row0 + 16 + lm; if (rA1 > n - 1) rA1 = n - 1;

    f32x4 acc[2][NT];
#pragma unroll
    for (int r = 0; r < 2; r++)
#pragma unroll
        for (int t = 0; t < NT; t++) acc[r][t] = (f32x4){0.f, 0.f, 0.f, 0.f};

    for (int kc = 0; kc < 128; kc += 32) {
        s8vec af[2];
        if (IN_F32) {
            const float* A = (const float*)Av;
#pragma unroll
            for (int r = 0; r < 2; r++) {
                const float* p = A + (size_t)(r ? rA1 : rA0) * 128 + quad * 8 + kc;
                float4 a = *(const float4*)p, b = *(const float4*)(p + 4);
                s8vec v;
                v[0] = (short)f2b(a.x); v[1] = (short)f2b(a.y);
                v[2] = (short)f2b(a.z); v[3] = (short)f2b(a.w);
                v[4] = (short)f2b(b.x); v[5] = (short)f2b(b.y);
                v[6] = (short)f2b(b.z); v[7] = (short)f2b(b.w);
                af[r] = v;
            }
        } else {
            const ushort* A = (const ushort*)Av;
            af[0] = *(const s8vec*)(A + (size_t)rA0 * 128 + quad * 8 + kc);
            af[1] = *(const s8vec*)(A + (size_t)rA1 * 128 + quad * 8 + kc);
        }
#pragma unroll
        for (int t = 0; t < NT; t++) {
            s8vec bf = *(const s8vec*)(Wt + (size_t)(t * 16 + lm) * 128 + kc + quad * 8);
            acc[0][t] = __builtin_amdgcn_mfma_f32_16x16x32_bf16(af[0], bf, acc[0][t], 0, 0, 0);
            acc[1][t] = __builtin_amdgcn_mfma_f32_16x16x32_bf16(af[1], bf, acc[1][t], 0, 0, 0);
        }
    }

#pragma unroll
    for (int r = 0; r < 2; r++) {
#pragma unroll
        for (int i = 0; i < 4; i++) {
            int rr = row0 + r * 16 + quad * 4 + i;
            if (rr < n) {
                float dv = SCALE ? dinv[rr] : 1.0f;
#pragma unroll
                for (int t = 0; t < NT; t++) {
                    int col = t * 16 + lm;
                    if (OUT_F32)
                        ((float*)Cv)[(size_t)rr * NCOL + col] = acc[r][t][i] + bias[col];
                    else
                        ((ushort*)Cv)[(size_t)rr * 128 + col] =
                            f2b(SCALE ? acc[r][t][i] * dv : acc[r][t][i]);
                }
            }
        }
    }
}

// fused: blocks [0,mmblocks) = layer-0 GEMM (scaled); rest = atomic-free CSR fill
__global__ __launch_bounds__(256) void k_mm0_fill(const void* __restrict__ Av,
                                                  const ushort* __restrict__ Wt,
                                                  const float* __restrict__ dinv,
                                                  void* __restrict__ Cv, int n, int mmblocks,
                                                  const int* __restrict__ src, const int* __restrict__ dst,
                                                  const int* __restrict__ rank,
                                                  const int* __restrict__ rowptr,
                                                  ushort* ed, int e) {
    if ((int)blockIdx.x >= mmblocks) {
        int base = ((int)blockIdx.x - mmblocks) * 1024 + threadIdx.x;
#pragma unroll
        for (int k = 0; k < 4; k++) {
            int i = base + k * 256;
            if (i < e) {
                int d = dst[i];
                int pos = rowptr[d] + rank[i];
                ed[pos] = (ushort)src[i];
            }
        }
        return;
    }
    mm_body<128, true, false, true>(Av, Wt, nullptr, dinv, Cv, n, blockIdx.x);
}

// ---------------- fused gather + next-layer GEMM ----------------
// Phase 1: 16 lanes/node gather (4-wide ILP, pipelined ed loads),
//          h = relu(dinv*(sum+self)+bias)+res; h rows -> LDS and (if !FINAL) global hout.
// Phase 2: 16-row MFMA tile: A from LDS, 4 waves x NCOL cols.
// Requires n % 16 == 0 (N=50000 = 3125*16).

template <int NCOL, bool RES_F32, bool FINAL>
__global__ __launch_bounds__(256) void k_gather_mm(const uint4* __restrict__ T4,
                                                   const int* __restrict__ rowptr,
                                                   const ushort* __restrict__ ed,
                                                   const float* __restrict__ dinv,
                                                   const float* __restrict__ biasL,
                                                   const void* __restrict__ resv,
                                                   uint4* __restrict__ hout,
                                                   const ushort* __restrict__ Wt,
                                                   const float* __restrict__ bias_out,
                                                   void* __restrict__ Cv, int n) {
    __shared__ uint4 As4[16 * 17];                 // 16 rows x 272 B (16B pad)
    ushort* As = (ushort*)As4;

    int tid = threadIdx.x;
    int nl = tid >> 4, ql = tid & 15;
    int qb = tid & 48;                              // quarter base within the wave
    int node = blockIdx.x * 16 + nl;

    // ---- phase 1: gather (software-pipelined ed loads) ----
    float acc[8] = {0.f, 0.f, 0.f, 0.f, 0.f, 0.f, 0.f, 0.f};
    int beg = rowptr[node], end = rowptr[node + 1];

    uint em = 0;
    if (beg < end) {
        int idx = beg + ql; if (idx > end - 1) idx = end - 1;
        em = ed[idx];
    }
    for (int base = beg; base < end; base += 16) {
        int m = end - base; if (m > 16) m = 16;
        // prefetch next batch's edge indices (overlaps with this batch's work)
        uint em_next = 0;
        int nb2 = base + 16;
        if (nb2 < end) {
            int idx = nb2 + ql; if (idx > end - 1) idx = end - 1;
            em_next = ed[idx];
        }
        int j = 0;
        for (; j + 4 <= m; j += 4) {
            int s0 = __shfl((int)em, qb + j);
            int s1 = __shfl((int)em, qb + j + 1);
            int s2 = __shfl((int)em, qb + j + 2);
            int s3 = __shfl((int)em, qb + j + 3);
            uint4 v0 = T4[(size_t)s0 * 16 + ql];
            uint4 v1 = T4[(size_t)s1 * 16 + ql];
            uint4 v2 = T4[(size_t)s2 * 16 + ql];
            uint4 v3 = T4[(size_t)s3 * 16 + ql];
            add8(acc, v0); add8(acc, v1); add8(acc, v2); add8(acc, v3);
        }
        for (; j < m; j++) {
            int s = __shfl((int)em, qb + j);
            uint4 v = T4[(size_t)s * 16 + ql];
            add8(acc, v);
        }
        em = em_next;
    }

    uint4 vs = T4[(size_t)node * 16 + ql];          // self (pre-scaled)
    add8(acc, vs);

    float di = dinv[node];
    float4 bv0 = ((const float4*)biasL)[ql * 2];
    float4 bv1 = ((const float4*)biasL)[ql * 2 + 1];
    float bb[8] = {bv0.x, bv0.y, bv0.z, bv0.w, bv1.x, bv1.y, bv1.z, bv1.w};

    float r[8];
    if (RES_F32) {
        float4 r0 = ((const float4*)resv)[(size_t)node * 32 + ql * 2];
        float4 r1 = ((const float4*)resv)[(size_t)node * 32 + ql * 2 + 1];
        r[0] = r0.x; r[1] = r0.y; r[2] = r0.z; r[3] = r0.w;
        r[4] = r1.x; r[5] = r1.y; r[6] = r1.z; r[7] = r1.w;
    } else {
        uint4 rv = ((const uint4*)resv)[(size_t)node * 16 + ql];
        r[0] = b2f_lo(rv.x); r[1] = b2f_hi(rv.x); r[2] = b2f_lo(rv.y); r[3] = b2f_hi(rv.y);
        r[4] = b2f_lo(rv.z); r[5] = b2f_hi(rv.z); r[6] = b2f_lo(rv.w); r[7] = b2f_hi(rv.w);
    }

    float o[8];
#pragma unroll
    for (int i = 0; i < 8; i++)
        o[i] = fmaxf(acc[i] * di + bb[i], 0.f) + r[i];

    uint4 ov;
    ov.x = (uint)f2b(o[0]) | ((uint)f2b(o[1]) << 16);
    ov.y = (uint)f2b(o[2]) | ((uint)f2b(o[3]) << 16);
    ov.z = (uint)f2b(o[4]) | ((uint)f2b(o[5]) << 16);
    ov.w = (uint)f2b(o[6]) | ((uint)f2b(o[7]) << 16);

    if (!FINAL) hout[(size_t)node * 16 + ql] = ov;
    *(uint4*)&As[nl * 136 + ql * 8] = ov;
    __syncthreads();

    // ---- phase 2: 16-row MFMA tile on this block's h rows ----
    constexpr int NT = NCOL / 64;                   // col tiles per wave (128->2, 64->1)
    int wave = tid >> 6;
    int lane = tid & 63;
    int quad = lane >> 4;
    int lm = lane & 15;

    f32x4 macc[NT];
#pragma unroll
    for (int t = 0; t < NT; t++) macc[t] = (f32x4){0.f, 0.f, 0.f, 0.f};

    for (int kc = 0; kc < 128; kc += 32) {
        s8vec af = *(const s8vec*)&As[lm * 136 + kc + quad * 8];
#pragma unroll
        for (int t = 0; t < NT; t++) {
            int col = wave * (16 * NT) + t * 16 + lm;
            s8vec bf = *(const s8vec*)(Wt + (size_t)col * 128 + kc + quad * 8);
            macc[t] = __builtin_amdgcn_mfma_f32_16x16x32_bf16(af, bf, macc[t], 0, 0, 0);
        }
    }

    int row0 = blockIdx.x * 16;
#pragma unroll
    for (int t = 0; t < NT; t++) {
        int col = wave * (16 * NT) + t * 16 + lm;
#pragma unroll
        for (int i = 0; i < 4; i++) {
            int rr = row0 + quad * 4 + i;
            if (FINAL)
                ((float*)Cv)[(size_t)rr * 64 + col] = macc[t][i] + bias_out[col];
            else
                ((ushort*)Cv)[(size_t)rr * 128 + col] = f2b(macc[t][i] * dinv[rr]);
        }
    }
}

// ---------------- launch ----------------

extern "C" void kernel_launch(void* const* d_in, const int* in_sizes, int n_in,
                              void* d_out, int out_size, void* d_ws, size_t ws_size,
                              hipStream_t stream) {
    const float* x  = (const float*)d_in[0];
    const int* eidx = (const int*)d_in[1];
    const float* W0 = (const float*)d_in[2];
    const float* b0 = (const float*)d_in[3];
    const float* W1 = (const float*)d_in[4];
    const float* b1 = (const float*)d_in[5];
    const float* W2 = (const float*)d_in[6];
    const float* b2 = (const float*)d_in[7];
    const float* Wo = (const float*)d_in[8];
    const float* bo = (const float*)d_in[9];
    float* out = (float*)d_out;

    const int N = N_NODES, E = N_EDGES;
    const int* srcI = eidx;
    const int* dstI = eidx + E;

    char* ws = (char*)d_ws;
    auto alloc = [&](size_t bytes) { char* p = ws; ws += (bytes + 255) / 256 * 256; return p; };
    int*    cnt    = (int*)alloc((size_t)N * 4);
    int*    rowptr = (int*)alloc((size_t)(N + 1) * 4);
    int*    rank   = (int*)alloc((size_t)E * 4);
    float*  dinv   = (float*)alloc((size_t)N * 4);
    ushort* ed     = (ushort*)alloc((size_t)E * 2);
    ushort* tA     = (ushort*)alloc((size_t)N * 128 * 2);
    ushort* tB     = (ushort*)alloc((size_t)N * 128 * 2);
    ushort* hAb    = (ushort*)alloc((size_t)N * 128 * 2);
    ushort* hBb    = (ushort*)alloc((size_t)N * 128 * 2);
    ushort* Wt0    = (ushort*)alloc(128 * 128 * 2);
    ushort* Wt1    = (ushort*)alloc(128 * 128 * 2);
    ushort* Wt2    = (ushort*)alloc(128 * 128 * 2);
    ushort* Wto    = (ushort*)alloc(64 * 128 * 2);

    dim3 b256(256), b512(512);

    const int mmGrid   = cdiv(N, 128);      // 391
    const int fillGrid = cdiv(E, 1024);     // 782
    const int gGrid    = N / 16;            // 3125 (exact)

    // prep (zero cnt ∥ weight transpose) -> count+rank -> one-kernel scan
    k_prep<<<196 + 224, b256, 0, stream>>>(cnt, W0, W1, W2, Wo, Wt0, Wt1, Wt2, Wto);
    k_count<<<cdiv(E, 256), b256, 0, stream>>>(dstI, cnt, rank, E);
    k_scan_all<<<NB512, b512, 0, stream>>>(cnt, rowptr, dinv, N, E, NB512);

    // layer-0 GEMM (pre-scaled -> tA) fused with atomic-free CSR fill
    k_mm0_fill<<<mmGrid + fillGrid, b256, 0, stream>>>(x, Wt0, dinv, tA, N, mmGrid,
                                                       srcI, dstI, rank, rowptr, ed, E);

    // gather0 (T=tA, res=x) + mm1 -> tB; h1 -> hAb
    k_gather_mm<128, true, false><<<gGrid, b256, 0, stream>>>(
        (const uint4*)tA, rowptr, ed, dinv, b0, x, (uint4*)hAb, Wt1, nullptr, tB, N);

    // gather1 (T=tB, res=hAb) + mm2 -> tA; h2 -> hBb
    k_gather_mm<128, false, false><<<gGrid, b256, 0, stream>>>(
        (const uint4*)tB, rowptr, ed, dinv, b1, hAb, (uint4*)hBb, Wt2, nullptr, tA, N);

    // gather2 (T=tA, res=hBb) + output projection -> out (fp32 + bias); h3 not materialized
    k_gather_mm<64, false, true><<<gGrid, b256, 0, stream>>>(
        (const uint4*)tA, rowptr, ed, dinv, b2, hBb, nullptr, Wto, bo, out, N);
}